// Round 1
// baseline (1252.263 us; speedup 1.0000x reference)
//
#include <hip/hip_runtime.h>
#include <hip/hip_bf16.h>

typedef __bf16 bf16;
typedef bf16 bf16x8 __attribute__((ext_vector_type(8)));
typedef bf16 bf16x4v __attribute__((ext_vector_type(4)));
typedef float f32x4 __attribute__((ext_vector_type(4)));

#define BB 8
#define CC 192
#define NH 6
#define HWN 16384
#define KSPLIT 16
#define KLEN (HWN / KSPLIT) /* 1024 */
#define KC 64

// ---------------------------------------------------------------------------
// Gram kernel: gram[type][b] = A * B^T over a K-slab, bf16 MFMA, fp32 atomics.
// type 0: X*Y^T, 1: X*X^T, 2: Y*Y^T.  Block: 512 thr = 8 waves, each wave a
// 96x48 piece of the 192x192 output (6x3 tiles of 16x16, K=32 MFMA steps).
// ---------------------------------------------------------------------------
__global__ __launch_bounds__(512) void gram_kernel(
    const float* __restrict__ x, const float* __restrict__ y,
    float* __restrict__ gram)
{
  const int ks = blockIdx.x, b = blockIdx.y, type = blockIdx.z;
  const int tid = threadIdx.x;
  const int lane = tid & 63, w = tid >> 6;
  const int rowbase = (w >> 2) * 96, colbase = (w & 3) * 48;
  const int lo = lane & 15, hi = lane >> 4;

  __shared__ bf16 tileA[CC * KC];  // row stride 128 B, XOR-swizzled
  __shared__ bf16 tileB[CC * KC];

  const float* asrc = (type == 2) ? y : x;
  const bf16* fragB = (type == 0) ? tileB : tileA;

  f32x4 acc[6][3];
  #pragma unroll
  for (int m = 0; m < 6; ++m)
    #pragma unroll
    for (int n = 0; n < 3; ++n) acc[m][n] = (f32x4){0.f, 0.f, 0.f, 0.f};

  const int k0 = ks * KLEN;

  for (int ch = 0; ch < KLEN / KC; ++ch) {
    const int nbase = k0 + ch * KC;
    // stage A tile (192 rows x 64 bf16); 512 thr x 6 float4 slots
    #pragma unroll
    for (int i = 0; i < 6; ++i) {
      int s = tid + 512 * i;
      int r = s >> 4, c4 = s & 15;
      const float4 v = *(const float4*)(asrc + ((size_t)(b * CC + r)) * HWN + nbase + c4 * 4);
      bf16x4v hv = { (bf16)v.x, (bf16)v.y, (bf16)v.z, (bf16)v.w };
      int byte = (r * (KC * 2) + c4 * 8) ^ ((r & 7) << 4);
      *(bf16x4v*)((char*)tileA + byte) = hv;
    }
    if (type == 0) {
      #pragma unroll
      for (int i = 0; i < 6; ++i) {
        int s = tid + 512 * i;
        int r = s >> 4, c4 = s & 15;
        const float4 v = *(const float4*)(y + ((size_t)(b * CC + r)) * HWN + nbase + c4 * 4);
        bf16x4v hv = { (bf16)v.x, (bf16)v.y, (bf16)v.z, (bf16)v.w };
        int byte = (r * (KC * 2) + c4 * 8) ^ ((r & 7) << 4);
        *(bf16x4v*)((char*)tileB + byte) = hv;
      }
    }
    __syncthreads();

    #pragma unroll
    for (int kk = 0; kk < KC; kk += 32) {
      const int kb = (kk + hi * 8) * 2;  // byte offset of 8 contiguous bf16
      bf16x8 bfr[3];
      #pragma unroll
      for (int nt = 0; nt < 3; ++nt) {
        int rB = colbase + nt * 16 + lo;
        int byte = (rB * (KC * 2) + kb) ^ ((rB & 7) << 4);
        bfr[nt] = *(const bf16x8*)((const char*)fragB + byte);
      }
      #pragma unroll
      for (int mt = 0; mt < 6; ++mt) {
        int rA = rowbase + mt * 16 + lo;
        int byte = (rA * (KC * 2) + kb) ^ ((rA & 7) << 4);
        bf16x8 afr = *(const bf16x8*)((const char*)tileA + byte);
        #pragma unroll
        for (int nt = 0; nt < 3; ++nt)
          acc[mt][nt] = __builtin_amdgcn_mfma_f32_16x16x32_bf16(afr, bfr[nt], acc[mt][nt], 0, 0, 0);
      }
    }
    __syncthreads();
  }

  // C/D layout (verified m89): col = lane&15, row = (lane>>4)*4 + reg
  float* gb = gram + ((size_t)(type * BB + b)) * CC * CC;
  #pragma unroll
  for (int mt = 0; mt < 6; ++mt)
    #pragma unroll
    for (int nt = 0; nt < 3; ++nt)
      #pragma unroll
      for (int r = 0; r < 4; ++r) {
        int rm = rowbase + mt * 16 + hi * 4 + r;
        int cn = colbase + nt * 16 + lo;
        atomicAdd(gb + rm * CC + cn, acc[mt][nt][r]);
      }
}

// ---------------------------------------------------------------------------
// s1: TUV[type][b] = gram[type][b] * Wsel^T   (192x192x192 fp32)
//     T = Gxy*Wk^T, U = Gxx*Wq^T, V2 = Gyy*Wk^T
// ---------------------------------------------------------------------------
__global__ void s1_kernel(const float* __restrict__ gram, const float* __restrict__ Wq,
                          const float* __restrict__ Wk, float* __restrict__ tuv)
{
  const int rc = blockIdx.x, b = blockIdx.y, type = blockIdx.z;
  const float* W = (type == 1) ? Wq : Wk;
  const float* G = gram + ((size_t)(type * BB + b)) * CC * CC;
  float* T = tuv + ((size_t)(type * BB + b)) * CC * CC;
  const int d = threadIdx.x;  // 0..191 = output column
  const int r0 = rc * 24;
  float acc[24];
  #pragma unroll
  for (int i = 0; i < 24; ++i) acc[i] = 0.f;
  for (int dc = 0; dc < 4; ++dc) {
    float4 w4[12];
    const float4* wp = (const float4*)(W + d * CC + dc * 48);
    #pragma unroll
    for (int j = 0; j < 12; ++j) w4[j] = wp[j];
    for (int ci = 0; ci < 24; ++ci) {
      const float4* g4 = (const float4*)(G + (r0 + ci) * CC + dc * 48);
      float a = acc[ci];
      #pragma unroll
      for (int j = 0; j < 12; ++j) {
        float4 g = g4[j];
        a += g.x * w4[j].x + g.y * w4[j].y + g.z * w4[j].z + g.w * w4[j].w;
      }
      acc[ci] = a;
    }
  }
  #pragma unroll
  for (int ci = 0; ci < 24; ++ci) T[(r0 + ci) * CC + d] = acc[ci];
}

// ---------------------------------------------------------------------------
// s2: per (b,head): S = Wq_head * T[:, head cols]; norms from U,V2;
//     softmax; Z_head = A * Wv_head_rows  (32x192). 256 threads.
// ---------------------------------------------------------------------------
__global__ void s2_kernel(const float* __restrict__ tuv, const float* __restrict__ Wq,
                          const float* __restrict__ Wk, const float* __restrict__ Wv,
                          const float* __restrict__ temperature, float* __restrict__ z)
{
  const int h = blockIdx.x, b = blockIdx.y;
  const int tid = threadIdx.x;
  const float* T  = tuv + ((size_t)(0 * BB + b)) * CC * CC;
  const float* U  = tuv + ((size_t)(1 * BB + b)) * CC * CC;
  const float* V2 = tuv + ((size_t)(2 * BB + b)) * CC * CC;
  __shared__ float sA[32][33];
  __shared__ float snq[32];
  __shared__ float snk[32];

  const int dd = tid & 31, cg = tid >> 5;
  float s[4] = {0.f, 0.f, 0.f, 0.f};
  for (int cp = 0; cp < CC; ++cp) {
    float tv = T[cp * CC + h * 32 + dd];
    #pragma unroll
    for (int i = 0; i < 4; ++i)
      s[i] += Wq[(h * 32 + cg + 8 * i) * CC + cp] * tv;
  }
  if (tid < 32) {
    float a = 0.f;
    for (int cp = 0; cp < CC; ++cp)
      a += Wq[(h * 32 + tid) * CC + cp] * U[cp * CC + h * 32 + tid];
    snq[tid] = fmaxf(sqrtf(fmaxf(a, 0.f)), 1e-12f);
  } else if (tid < 64) {
    int t2 = tid - 32;
    float a = 0.f;
    for (int cp = 0; cp < CC; ++cp)
      a += Wk[(h * 32 + t2) * CC + cp] * V2[cp * CC + h * 32 + t2];
    snk[t2] = fmaxf(sqrtf(fmaxf(a, 0.f)), 1e-12f);
  }
  __syncthreads();

  const float temp = temperature[h];
  const float rk = 1.f / snk[dd];
  #pragma unroll
  for (int i = 0; i < 4; ++i) {
    int ccr = cg + 8 * i;
    float l = s[i] * (1.f / snq[ccr]) * rk * temp;
    float m = l;
    #pragma unroll
    for (int msk = 16; msk >= 1; msk >>= 1) m = fmaxf(m, __shfl_xor(m, msk));
    float p = expf(l - m);
    float su = p;
    #pragma unroll
    for (int msk = 16; msk >= 1; msk >>= 1) su += __shfl_xor(su, msk);
    sA[ccr][dd] = p / su;
  }
  __syncthreads();

  const int c2l = tid & 63, ccg = tid >> 6;
  float za[8][3];
  #pragma unroll
  for (int i = 0; i < 8; ++i)
    #pragma unroll
    for (int j = 0; j < 3; ++j) za[i][j] = 0.f;
  for (int d2 = 0; d2 < 32; ++d2) {
    float wv[3];
    #pragma unroll
    for (int j = 0; j < 3; ++j) wv[j] = Wv[(h * 32 + d2) * CC + c2l + 64 * j];
    #pragma unroll
    for (int i = 0; i < 8; ++i) {
      float a = sA[ccg * 8 + i][d2];
      #pragma unroll
      for (int j = 0; j < 3; ++j) za[i][j] += a * wv[j];
    }
  }
  #pragma unroll
  for (int i = 0; i < 8; ++i)
    #pragma unroll
    for (int j = 0; j < 3; ++j)
      z[((size_t)b * CC + h * 32 + ccg * 8 + i) * CC + c2l + 64 * j] = za[i][j];
}

// ---------------------------------------------------------------------------
// s3: PT[b][d][o] = (Wo * Z_b)[o][d]   (stored transposed for f_kernel)
// ---------------------------------------------------------------------------
__global__ void s3_kernel(const float* __restrict__ z, const float* __restrict__ Wo,
                          float* __restrict__ pt)
{
  const int oc = blockIdx.x, b = blockIdx.y;
  const int d = threadIdx.x;  // 0..191
  const int o0 = oc * 24;
  const float* Z = z + (size_t)b * CC * CC;
  float acc[24];
  #pragma unroll
  for (int i = 0; i < 24; ++i) acc[i] = 0.f;
  for (int c = 0; c < CC; ++c) {
    float zv = Z[c * CC + d];
    #pragma unroll
    for (int oi = 0; oi < 24; ++oi)
      acc[oi] += Wo[(o0 + oi) * CC + c] * zv;
  }
  float* P = pt + (size_t)b * CC * CC;
  #pragma unroll
  for (int oi = 0; oi < 24; ++oi)
    P[d * CC + o0 + oi] = acc[oi];
}

// ---------------------------------------------------------------------------
// f: out[b][o][n] = sum_d PT[b][d][o] * Y[b][d][n]. Block: 4 waves, each wave
// owns 48 rows (o) x 64 cols (n). P loads are wave-uniform broadcasts.
// ---------------------------------------------------------------------------
__global__ __launch_bounds__(256) void f_kernel(const float* __restrict__ y,
                                                const float* __restrict__ pt,
                                                float* __restrict__ out)
{
  const int nc = blockIdx.x, b = blockIdx.y;
  const int tid = threadIdx.x;
  const int lane = tid & 63, mg = tid >> 6;
  const size_t ybase = (size_t)b * CC * HWN + nc * 64 + lane;
  const float* P = pt + (size_t)b * CC * CC + mg * 48;
  float acc[48];
  #pragma unroll
  for (int i = 0; i < 48; ++i) acc[i] = 0.f;
  for (int d = 0; d < CC; ++d) {
    float yv = y[ybase + (size_t)d * HWN];
    const float4* p4 = (const float4*)(P + d * CC);
    #pragma unroll
    for (int j = 0; j < 12; ++j) {
      float4 pv = p4[j];
      acc[j * 4 + 0] += pv.x * yv;
      acc[j * 4 + 1] += pv.y * yv;
      acc[j * 4 + 2] += pv.z * yv;
      acc[j * 4 + 3] += pv.w * yv;
    }
  }
  const size_t ob = ((size_t)b * CC + mg * 48) * HWN + nc * 64 + lane;
  #pragma unroll
  for (int m = 0; m < 48; ++m)
    out[ob + (size_t)m * HWN] = acc[m];
}

extern "C" void kernel_launch(void* const* d_in, const int* in_sizes, int n_in,
                              void* d_out, int out_size, void* d_ws, size_t ws_size,
                              hipStream_t stream)
{
  (void)in_sizes; (void)n_in; (void)out_size; (void)ws_size;
  const float* x  = (const float*)d_in[0];
  const float* y  = (const float*)d_in[1];
  const float* Wq = (const float*)d_in[2];
  const float* Wk = (const float*)d_in[3];
  const float* Wv = (const float*)d_in[4];
  const float* Wo = (const float*)d_in[5];
  const float* temperature = (const float*)d_in[6];
  float* out = (float*)d_out;

  float* ws   = (float*)d_ws;
  float* gram = ws;                       // 3*8*192*192
  float* tuv  = gram + 3 * BB * CC * CC;  // 3*8*192*192
  float* zbuf = tuv + 3 * BB * CC * CC;   // 8*192*192
  float* ptb  = zbuf + BB * CC * CC;      // 8*192*192  (~9.4 MB total)

  hipMemsetAsync(gram, 0, (size_t)3 * BB * CC * CC * sizeof(float), stream);
  gram_kernel<<<dim3(KSPLIT, BB, 3), 512, 0, stream>>>(x, y, gram);
  s1_kernel<<<dim3(8, BB, 3), 192, 0, stream>>>(gram, Wq, Wk, tuv);
  s2_kernel<<<dim3(NH, BB), 256, 0, stream>>>(tuv, Wq, Wk, Wv, temperature, zbuf);
  s3_kernel<<<dim3(8, BB), 192, 0, stream>>>(zbuf, Wo, ptb);
  f_kernel<<<dim3(HWN / 64, BB), 256, 0, stream>>>(y, ptb, out);
}

// Round 3
// 522.468 us; speedup vs baseline: 2.3968x; 2.3968x over previous
//
#include <hip/hip_runtime.h>
#include <hip/hip_bf16.h>

typedef __bf16 bf16;
typedef bf16 bf16x8 __attribute__((ext_vector_type(8)));
typedef bf16 bf16x4v __attribute__((ext_vector_type(4)));
typedef float f32x4 __attribute__((ext_vector_type(4)));

#define BB 8
#define CC 192
#define NH 6
#define HWN 16384
#define KSPLIT 16
#define KLEN (HWN / KSPLIT) /* 1024 */
#define KC 64
#define GSLAB (3 * BB * CC * CC) /* floats per partial slab = 884736 */

// ---------------------------------------------------------------------------
// Gram kernel: partial[ks][type][b] = A * B^T over a K-slab, bf16 MFMA.
// type 0: X*Y^T, 1: X*X^T, 2: Y*Y^T.  Block: 512 thr = 8 waves, each wave a
// 96x48 piece of the 192x192 output. use_atomic=1 falls back to atomicAdd
// into the final gram buffer (small-ws fallback).
// ---------------------------------------------------------------------------
__global__ __launch_bounds__(512) void gram_kernel(
    const float* __restrict__ x, const float* __restrict__ y,
    float* __restrict__ dst, int use_atomic)
{
  const int ks = blockIdx.x, b = blockIdx.y, type = blockIdx.z;
  const int tid = threadIdx.x;
  const int lane = tid & 63, w = tid >> 6;
  const int rowbase = (w >> 2) * 96, colbase = (w & 3) * 48;
  const int lo = lane & 15, hi = lane >> 4;

  __shared__ bf16 tileA[CC * KC];  // row stride 128 B, XOR-swizzled
  __shared__ bf16 tileB[CC * KC];

  const float* asrc = (type == 2) ? y : x;
  const bf16* fragB = (type == 0) ? tileB : tileA;

  f32x4 acc[6][3];
  #pragma unroll
  for (int m = 0; m < 6; ++m)
    #pragma unroll
    for (int n = 0; n < 3; ++n) acc[m][n] = (f32x4){0.f, 0.f, 0.f, 0.f};

  const int k0 = ks * KLEN;

  for (int ch = 0; ch < KLEN / KC; ++ch) {
    const int nbase = k0 + ch * KC;
    #pragma unroll
    for (int i = 0; i < 6; ++i) {
      int s = tid + 512 * i;
      int r = s >> 4, c4 = s & 15;
      const float4 v = *(const float4*)(asrc + ((size_t)(b * CC + r)) * HWN + nbase + c4 * 4);
      bf16x4v hv = { (bf16)v.x, (bf16)v.y, (bf16)v.z, (bf16)v.w };
      int byte = (r * (KC * 2) + c4 * 8) ^ ((r & 7) << 4);
      *(bf16x4v*)((char*)tileA + byte) = hv;
    }
    if (type == 0) {
      #pragma unroll
      for (int i = 0; i < 6; ++i) {
        int s = tid + 512 * i;
        int r = s >> 4, c4 = s & 15;
        const float4 v = *(const float4*)(y + ((size_t)(b * CC + r)) * HWN + nbase + c4 * 4);
        bf16x4v hv = { (bf16)v.x, (bf16)v.y, (bf16)v.z, (bf16)v.w };
        int byte = (r * (KC * 2) + c4 * 8) ^ ((r & 7) << 4);
        *(bf16x4v*)((char*)tileB + byte) = hv;
      }
    }
    __syncthreads();

    #pragma unroll
    for (int kk = 0; kk < KC; kk += 32) {
      const int kb = (kk + hi * 8) * 2;
      bf16x8 bfr[3];
      #pragma unroll
      for (int nt = 0; nt < 3; ++nt) {
        int rB = colbase + nt * 16 + lo;
        int byte = (rB * (KC * 2) + kb) ^ ((rB & 7) << 4);
        bfr[nt] = *(const bf16x8*)((const char*)fragB + byte);
      }
      #pragma unroll
      for (int mt = 0; mt < 6; ++mt) {
        int rA = rowbase + mt * 16 + lo;
        int byte = (rA * (KC * 2) + kb) ^ ((rA & 7) << 4);
        bf16x8 afr = *(const bf16x8*)((const char*)tileA + byte);
        #pragma unroll
        for (int nt = 0; nt < 3; ++nt)
          acc[mt][nt] = __builtin_amdgcn_mfma_f32_16x16x32_bf16(afr, bfr[nt], acc[mt][nt], 0, 0, 0);
      }
    }
    __syncthreads();
  }

  // C/D layout: col = lane&15, row = (lane>>4)*4 + reg
  if (use_atomic) {
    float* gb = dst + ((size_t)(type * BB + b)) * CC * CC;
    #pragma unroll
    for (int mt = 0; mt < 6; ++mt)
      #pragma unroll
      for (int nt = 0; nt < 3; ++nt)
        #pragma unroll
        for (int r = 0; r < 4; ++r) {
          int rm = rowbase + mt * 16 + hi * 4 + r;
          int cn = colbase + nt * 16 + lo;
          atomicAdd(gb + rm * CC + cn, acc[mt][nt][r]);
        }
  } else {
    float* gb = dst + (size_t)ks * GSLAB + ((size_t)(type * BB + b)) * CC * CC;
    #pragma unroll
    for (int mt = 0; mt < 6; ++mt)
      #pragma unroll
      for (int nt = 0; nt < 3; ++nt)
        #pragma unroll
        for (int r = 0; r < 4; ++r) {
          int rm = rowbase + mt * 16 + hi * 4 + r;
          int cn = colbase + nt * 16 + lo;
          gb[rm * CC + cn] = acc[mt][nt][r];
        }
  }
}

// Sum KSPLIT partial slabs -> gram.
__global__ void reduce_kernel(const float* __restrict__ gpart, float* __restrict__ gram)
{
  const size_t i = (size_t)blockIdx.x * 256 + threadIdx.x;
  float a = 0.f;
  #pragma unroll
  for (int s = 0; s < KSPLIT; ++s) a += gpart[(size_t)s * GSLAB + i];
  gram[i] = a;
}

// ---------------------------------------------------------------------------
// s1: TUV[type][b] = gram[type][b] * Wsel^T   (192x192x192 fp32)
// ---------------------------------------------------------------------------
__global__ void s1_kernel(const float* __restrict__ gram, const float* __restrict__ Wq,
                          const float* __restrict__ Wk, float* __restrict__ tuv)
{
  const int rc = blockIdx.x, b = blockIdx.y, type = blockIdx.z;
  const float* W = (type == 1) ? Wq : Wk;
  const float* G = gram + ((size_t)(type * BB + b)) * CC * CC;
  float* T = tuv + ((size_t)(type * BB + b)) * CC * CC;
  const int d = threadIdx.x;
  const int r0 = rc * 24;
  float acc[24];
  #pragma unroll
  for (int i = 0; i < 24; ++i) acc[i] = 0.f;
  for (int dc = 0; dc < 4; ++dc) {
    float4 w4[12];
    const float4* wp = (const float4*)(W + d * CC + dc * 48);
    #pragma unroll
    for (int j = 0; j < 12; ++j) w4[j] = wp[j];
    for (int ci = 0; ci < 24; ++ci) {
      const float4* g4 = (const float4*)(G + (r0 + ci) * CC + dc * 48);
      float a = acc[ci];
      #pragma unroll
      for (int j = 0; j < 12; ++j) {
        float4 g = g4[j];
        a += g.x * w4[j].x + g.y * w4[j].y + g.z * w4[j].z + g.w * w4[j].w;
      }
      acc[ci] = a;
    }
  }
  #pragma unroll
  for (int ci = 0; ci < 24; ++ci) T[(r0 + ci) * CC + d] = acc[ci];
}

// ---------------------------------------------------------------------------
// s2: per (b,head): S, norms, softmax, Z_head = A * Wv_head_rows.
// ---------------------------------------------------------------------------
__global__ void s2_kernel(const float* __restrict__ tuv, const float* __restrict__ Wq,
                          const float* __restrict__ Wk, const float* __restrict__ Wv,
                          const float* __restrict__ temperature, float* __restrict__ z)
{
  const int h = blockIdx.x, b = blockIdx.y;
  const int tid = threadIdx.x;
  const float* T  = tuv + ((size_t)(0 * BB + b)) * CC * CC;
  const float* U  = tuv + ((size_t)(1 * BB + b)) * CC * CC;
  const float* V2 = tuv + ((size_t)(2 * BB + b)) * CC * CC;
  __shared__ float sA[32][33];
  __shared__ float snq[32];
  __shared__ float snk[32];

  const int dd = tid & 31, cg = tid >> 5;
  float s[4] = {0.f, 0.f, 0.f, 0.f};
  for (int cp = 0; cp < CC; ++cp) {
    float tv = T[cp * CC + h * 32 + dd];
    #pragma unroll
    for (int i = 0; i < 4; ++i)
      s[i] += Wq[(h * 32 + cg + 8 * i) * CC + cp] * tv;
  }
  if (tid < 32) {
    float a = 0.f;
    for (int cp = 0; cp < CC; ++cp)
      a += Wq[(h * 32 + tid) * CC + cp] * U[cp * CC + h * 32 + tid];
    snq[tid] = fmaxf(sqrtf(fmaxf(a, 0.f)), 1e-12f);
  } else if (tid < 64) {
    int t2 = tid - 32;
    float a = 0.f;
    for (int cp = 0; cp < CC; ++cp)
      a += Wk[(h * 32 + t2) * CC + cp] * V2[cp * CC + h * 32 + t2];
    snk[t2] = fmaxf(sqrtf(fmaxf(a, 0.f)), 1e-12f);
  }
  __syncthreads();

  const float temp = temperature[h];
  const float rk = 1.f / snk[dd];
  #pragma unroll
  for (int i = 0; i < 4; ++i) {
    int ccr = cg + 8 * i;
    float l = s[i] * (1.f / snq[ccr]) * rk * temp;
    float m = l;
    #pragma unroll
    for (int msk = 16; msk >= 1; msk >>= 1) m = fmaxf(m, __shfl_xor(m, msk));
    float p = expf(l - m);
    float su = p;
    #pragma unroll
    for (int msk = 16; msk >= 1; msk >>= 1) su += __shfl_xor(su, msk);
    sA[ccr][dd] = p / su;
  }
  __syncthreads();

  const int c2l = tid & 63, ccg = tid >> 6;
  float za[8][3];
  #pragma unroll
  for (int i = 0; i < 8; ++i)
    #pragma unroll
    for (int j = 0; j < 3; ++j) za[i][j] = 0.f;
  for (int d2 = 0; d2 < 32; ++d2) {
    float wv[3];
    #pragma unroll
    for (int j = 0; j < 3; ++j) wv[j] = Wv[(h * 32 + d2) * CC + c2l + 64 * j];
    #pragma unroll
    for (int i = 0; i < 8; ++i) {
      float a = sA[ccg * 8 + i][d2];
      #pragma unroll
      for (int j = 0; j < 3; ++j) za[i][j] += a * wv[j];
    }
  }
  #pragma unroll
  for (int i = 0; i < 8; ++i)
    #pragma unroll
    for (int j = 0; j < 3; ++j)
      z[((size_t)b * CC + h * 32 + ccg * 8 + i) * CC + c2l + 64 * j] = za[i][j];
}

// ---------------------------------------------------------------------------
// s3: P[b][o][d] = (Wo * Z_b)[o][d], emitted as bf16 for f_kernel's A operand.
// ---------------------------------------------------------------------------
__global__ void s3_kernel(const float* __restrict__ z, const float* __restrict__ Wo,
                          bf16* __restrict__ pb)
{
  const int oc = blockIdx.x, b = blockIdx.y;
  const int d = threadIdx.x;  // 0..191
  const int o0 = oc * 24;
  const float* Z = z + (size_t)b * CC * CC;
  float acc[24];
  #pragma unroll
  for (int i = 0; i < 24; ++i) acc[i] = 0.f;
  for (int c = 0; c < CC; ++c) {
    float zv = Z[c * CC + d];
    #pragma unroll
    for (int oi = 0; oi < 24; ++oi)
      acc[oi] += Wo[(o0 + oi) * CC + c] * zv;
  }
  bf16* P = pb + (size_t)b * CC * CC;
  #pragma unroll
  for (int oi = 0; oi < 24; ++oi)
    P[(o0 + oi) * CC + d] = (bf16)acc[oi];
}

// ---------------------------------------------------------------------------
// f: out[b] = P_b (192x192 bf16) * Y_b (192x16384), MFMA, fp32 out.
// Block: 4 waves, each wave 48 o-rows x 64 n-cols; K=192 in 6 steps of 32.
// Y tile transposed into LDS via bf16 scatter; B frag = 8-scalar LDS gather.
// ---------------------------------------------------------------------------
__global__ __launch_bounds__(256) void f_kernel(const float* __restrict__ y,
                                                const bf16* __restrict__ pb,
                                                float* __restrict__ out)
{
  const int nc = blockIdx.x, b = blockIdx.y;
  const int tid = threadIdx.x;
  const int lane = tid & 63, w = tid >> 6;
  const int lo = lane & 15, hi = lane >> 4;
  const int rowbase = w * 48;
  __shared__ bf16 yt[32][68];  // [d][n] pitch 68 -> 2-way-max bank pattern

  f32x4 acc[3][4];
  #pragma unroll
  for (int m = 0; m < 3; ++m)
    #pragma unroll
    for (int n = 0; n < 4; ++n) acc[m][n] = (f32x4){0.f, 0.f, 0.f, 0.f};

  const int sd = tid >> 4;        // staging row 0..15
  const int sn = (tid & 15) * 4;  // staging col group

  for (int ks = 0; ks < 6; ++ks) {
    const int d0 = ks * 32;
    __syncthreads();
    #pragma unroll
    for (int p = 0; p < 2; ++p) {
      int d = sd + p * 16;
      const float4 v = *(const float4*)(y + ((size_t)(b * CC + d0 + d)) * HWN + nc * 64 + sn);
      bf16x4v hv = { (bf16)v.x, (bf16)v.y, (bf16)v.z, (bf16)v.w };
      *(bf16x4v*)(&yt[d][sn]) = hv;
    }
    __syncthreads();

    bf16x8 pa[3];
    #pragma unroll
    for (int mt = 0; mt < 3; ++mt)
      pa[mt] = *(const bf16x8*)(pb + ((size_t)(b * CC + rowbase + mt * 16 + lo)) * CC + d0 + hi * 8);

    #pragma unroll
    for (int nt = 0; nt < 4; ++nt) {
      bf16x8 bq;
      #pragma unroll
      for (int j = 0; j < 8; ++j) bq[j] = yt[hi * 8 + j][nt * 16 + lo];
      #pragma unroll
      for (int mt = 0; mt < 3; ++mt)
        acc[mt][nt] = __builtin_amdgcn_mfma_f32_16x16x32_bf16(pa[mt], bq, acc[mt][nt], 0, 0, 0);
    }
  }

  #pragma unroll
  for (int mt = 0; mt < 3; ++mt)
    #pragma unroll
    for (int nt = 0; nt < 4; ++nt)
      #pragma unroll
      for (int r = 0; r < 4; ++r) {
        int o = rowbase + mt * 16 + hi * 4 + r;
        out[((size_t)(b * CC + o)) * HWN + nc * 64 + nt * 16 + lo] = acc[mt][nt][r];
      }
}

extern "C" void kernel_launch(void* const* d_in, const int* in_sizes, int n_in,
                              void* d_out, int out_size, void* d_ws, size_t ws_size,
                              hipStream_t stream)
{
  (void)in_sizes; (void)n_in; (void)out_size;
  const float* x  = (const float*)d_in[0];
  const float* y  = (const float*)d_in[1];
  const float* Wq = (const float*)d_in[2];
  const float* Wk = (const float*)d_in[3];
  const float* Wv = (const float*)d_in[4];
  const float* Wo = (const float*)d_in[5];
  const float* temperature = (const float*)d_in[6];
  float* out = (float*)d_out;

  float* ws = (float*)d_ws;
  const size_t G = (size_t)GSLAB;
  const size_t need_part =
      (KSPLIT * G + G + G + (size_t)BB * CC * CC) * sizeof(float) +
      (size_t)BB * CC * CC * sizeof(bf16);

  float *gram, *tuv, *zbuf;
  bf16* pbuf;
  if (ws_size >= need_part) {
    float* gpart = ws;
    gram = gpart + KSPLIT * G;
    tuv  = gram + G;
    zbuf = tuv + G;
    pbuf = (bf16*)(zbuf + (size_t)BB * CC * CC);
    gram_kernel<<<dim3(KSPLIT, BB, 3), 512, 0, stream>>>(x, y, gpart, 0);
    reduce_kernel<<<GSLAB / 256, 256, 0, stream>>>(gpart, gram);
  } else {
    gram = ws;
    tuv  = gram + G;
    zbuf = tuv + G;
    pbuf = (bf16*)(zbuf + (size_t)BB * CC * CC);
    hipMemsetAsync(gram, 0, G * sizeof(float), stream);
    gram_kernel<<<dim3(KSPLIT, BB, 3), 512, 0, stream>>>(x, y, gram, 1);
  }

  s1_kernel<<<dim3(8, BB, 3), 192, 0, stream>>>(gram, Wq, Wk, tuv);
  s2_kernel<<<dim3(NH, BB), 256, 0, stream>>>(tuv, Wq, Wk, Wv, temperature, zbuf);
  s3_kernel<<<dim3(8, BB), 192, 0, stream>>>(zbuf, Wo, pbuf);
  f_kernel<<<dim3(HWN / 64, BB), 256, 0, stream>>>(y, pbuf, out);
}